// Round 2
// baseline (1284.301 us; speedup 1.0000x reference)
//
#include <hip/hip_runtime.h>

#define N_NODES 100000
#define N_EDGES 1600000
#define IN_F   128
#define HID_F  64
#define Z_F    32
#define NBUK   782          // ceil(100000/128) buckets of 128 dst nodes
#define BCAP   3072         // bucket capacity (mean 2046, sigma ~45)
#define P1T    4096         // edges per phase1 block
#define P1_BLOCKS ((N_EDGES + P1T - 1) / P1T)   // 391
#define DEG_PAD 100352      // N_NODES padded so DEG_PAD*4 is a 256B multiple

typedef unsigned int uint32;
typedef __attribute__((ext_vector_type(8))) short bf16x8;
typedef __attribute__((ext_vector_type(4))) float f32x4;

__device__ __forceinline__ unsigned short f2bf(float f) {
    unsigned u = __float_as_uint(f);
    u = (u + 0x7FFF + ((u >> 16) & 1)) >> 16;   // RNE
    return (unsigned short)u;
}
__device__ __forceinline__ uint32 pack2bf(float lo, float hi) {
    return (uint32)f2bf(lo) | ((uint32)f2bf(hi) << 16);
}
__device__ __forceinline__ float bflo(uint32 u) { return __uint_as_float(u << 16); }
__device__ __forceinline__ float bfhi(uint32 u) { return __uint_as_float(u & 0xFFFF0000u); }

// ---------------- phase 1: bucket partition + per-node degree; last block: weights
__global__ __launch_bounds__(256) void phase1_kernel(const int* __restrict__ ei,
                                                     int* __restrict__ gcur,
                                                     uint32* __restrict__ pairs,
                                                     int* __restrict__ deg,
                                                     const float* __restrict__ W1,
                                                     const float* __restrict__ W2,
                                                     const float* __restrict__ Wmu,
                                                     const float* __restrict__ Wlv,
                                                     unsigned short* __restrict__ Wt1,
                                                     unsigned short* __restrict__ Wt2,
                                                     unsigned short* __restrict__ Wth) {
    if (blockIdx.x == P1_BLOCKS) {   // weight transpose/convert block (no graph dep)
        int t = threadIdx.x;
        for (int i = t; i < IN_F * HID_F; i += 256) {        // Wt1[n][k] = W1[k][n]
            int n = i >> 7, k = i & 127;
            Wt1[i] = f2bf(W1[k * HID_F + n]);
        }
        for (int i = t; i < HID_F * Z_F; i += 256) {         // Wt2[n][k] = W2[k][n]
            int n = i >> 6, k = i & 63;
            Wt2[i] = f2bf(W2[k * Z_F + n]);
        }
        for (int i = t; i < Z_F * 64; i += 256) {            // Wth[n][k]: n<32 mu, else lv
            int n = i >> 5, k = i & 31;
            Wth[i] = f2bf(n < 32 ? Wmu[k * Z_F + n] : Wlv[k * Z_F + (n - 32)]);
        }
        return;
    }
    __shared__ int hist[NBUK];
    __shared__ int lbase[NBUK];
    __shared__ int gbase[NBUK];
    __shared__ int lcur[NBUK];
    __shared__ uint32 stage[P1T];
    __shared__ unsigned short sbid[P1T];
    __shared__ int part[256];
    int tid = threadIdx.x;
    int e0 = blockIdx.x * P1T;
    int ecnt = N_EDGES - e0; if (ecnt > P1T) ecnt = P1T;
    for (int b = tid; b < NBUK; b += 256) { hist[b] = 0; lcur[b] = 0; }
    __syncthreads();
    int myd[16];                      // dst cached in regs: read ei's dst half ONCE
#pragma unroll
    for (int i = 0; i < 16; i++) {
        int k = tid + i * 256;
        myd[i] = (k < ecnt) ? ei[N_EDGES + e0 + k] : -1;
    }
#pragma unroll
    for (int i = 0; i < 16; i++)
        if (myd[i] >= 0) {
            atomicAdd(&hist[myd[i] >> 7], 1);
            atomicAdd(&deg[myd[i]], 1);          // global per-node in-degree
        }
    __syncthreads();
    int t4 = tid * 4;
    int l0 = 0, l1 = 0, l2 = 0, l3 = 0, s = 0;
    if (t4 + 0 < NBUK) { l0 = hist[t4 + 0]; s += l0; }
    if (t4 + 1 < NBUK) { l1 = hist[t4 + 1]; s += l1; }
    if (t4 + 2 < NBUK) { l2 = hist[t4 + 2]; s += l2; }
    if (t4 + 3 < NBUK) { l3 = hist[t4 + 3]; s += l3; }
    part[tid] = s;
    __syncthreads();
    for (int off = 1; off < 256; off <<= 1) {
        int add = (tid >= off) ? part[tid - off] : 0;
        __syncthreads();
        part[tid] += add;
        __syncthreads();
    }
    int run = part[tid] - s;
    if (t4 + 0 < NBUK) { lbase[t4 + 0] = run; run += l0; }
    if (t4 + 1 < NBUK) { lbase[t4 + 1] = run; run += l1; }
    if (t4 + 2 < NBUK) { lbase[t4 + 2] = run; run += l2; }
    if (t4 + 3 < NBUK) { lbase[t4 + 3] = run; run += l3; }
    for (int b = tid; b < NBUK; b += 256) {
        int h = hist[b];
        gbase[b] = h ? atomicAdd(&gcur[b], h) : 0;
    }
    __syncthreads();
#pragma unroll
    for (int i = 0; i < 16; i++) {
        int k = tid + i * 256;
        if (k < ecnt) {
            int sN = ei[e0 + k];
            int d  = myd[i];
            int b = d >> 7;
            int slot = lbase[b] + atomicAdd(&lcur[b], 1);
            stage[slot] = (uint32)sN | ((uint32)(d & 127) << 17);
            sbid[slot] = (unsigned short)b;
        }
    }
    __syncthreads();
    for (int k = tid; k < ecnt; k += 256) {
        int b = sbid[k];
        int r = gbase[b] + (k - lbase[b]);
        if (r < BCAP) pairs[(size_t)b * BCAP + r] = stage[k];
    }
}

// ---------------- GEMM1: t1 = bf16(dinv * (x@W1)) in xpose8 row layout -----------
// t1 row storage pos p holds feat 8*(p&7)+(p>>3)  (8x8 transpose) so that an
// aggregation lane's uint4 (shorts 8f..8f+7) = feats {f, f+8, ..., f+56}.
__global__ __launch_bounds__(256) void gemm1_kernel(const float* __restrict__ x,
                                                    const unsigned short* __restrict__ Wt1,
                                                    const int* __restrict__ deg,
                                                    unsigned short* __restrict__ t1) {
    __shared__ unsigned short Cs[64 * 72];
    __shared__ float dv[64];
    int tid = threadIdx.x;
    int node0 = blockIdx.x * 64;
    if (tid < 64) {
        int n = node0 + tid;
        dv[tid] = (n < N_NODES) ? rsqrtf((float)(deg[n] + 1)) : 0.f;
    }
    __syncthreads();
    int w = tid >> 6, lane = tid & 63;
    int m = lane & 15, quad = lane >> 4;
    int row = w * 16 + m;
    int node = node0 + row;
    const float* xr = x + (size_t)min(node, N_NODES - 1) * IN_F;
    f32x4 acc0 = {0.f, 0.f, 0.f, 0.f};
    f32x4 acc1 = acc0, acc2 = acc0, acc3 = acc0;
#pragma unroll
    for (int ks = 0; ks < 4; ks++) {
        int kb = ks * 32 + quad * 8;
        float4 f0 = *(const float4*)(xr + kb);
        float4 f1 = *(const float4*)(xr + kb + 4);
        union { bf16x8 v; unsigned short u[8]; } A;
        A.u[0] = f2bf(f0.x); A.u[1] = f2bf(f0.y); A.u[2] = f2bf(f0.z); A.u[3] = f2bf(f0.w);
        A.u[4] = f2bf(f1.x); A.u[5] = f2bf(f1.y); A.u[6] = f2bf(f1.z); A.u[7] = f2bf(f1.w);
        bf16x8 b0 = *(const bf16x8*)&Wt1[(0 * 16 + m) * IN_F + kb];
        bf16x8 b1 = *(const bf16x8*)&Wt1[(1 * 16 + m) * IN_F + kb];
        bf16x8 b2 = *(const bf16x8*)&Wt1[(2 * 16 + m) * IN_F + kb];
        bf16x8 b3 = *(const bf16x8*)&Wt1[(3 * 16 + m) * IN_F + kb];
        acc0 = __builtin_amdgcn_mfma_f32_16x16x32_bf16(A.v, b0, acc0, 0, 0, 0);
        acc1 = __builtin_amdgcn_mfma_f32_16x16x32_bf16(A.v, b1, acc1, 0, 0, 0);
        acc2 = __builtin_amdgcn_mfma_f32_16x16x32_bf16(A.v, b2, acc2, 0, 0, 0);
        acc3 = __builtin_amdgcn_mfma_f32_16x16x32_bf16(A.v, b3, acc3, 0, 0, 0);
    }
    int rbase = w * 16 + quad * 4;
    int cbase = 8 * (m & 7) + (m >> 3);   // xpose8 column; ntile adds +2*nt
#pragma unroll
    for (int reg = 0; reg < 4; reg++) {
        int r = rbase + reg;
        float d = dv[r];
        Cs[r * 72 + cbase + 0] = f2bf(acc0[reg] * d);
        Cs[r * 72 + cbase + 2] = f2bf(acc1[reg] * d);
        Cs[r * 72 + cbase + 4] = f2bf(acc2[reg] * d);
        Cs[r * 72 + cbase + 6] = f2bf(acc3[reg] * d);
    }
    __syncthreads();
#pragma unroll
    for (int it = 0; it < 4; it++) {
        int idx = it * 256 + tid;
        int r = idx >> 4, c = idx & 15;
        int nd = node0 + r;
        if (nd < N_NODES) {
            uint2 vv = *(const uint2*)&Cs[r * 72 + c * 4];
            *(uint2*)&t1[(size_t)nd * HID_F + c * 4] = vv;
        }
    }
}

// ---------------- FUSED agg1+gemm2: per-bucket LDS f32 scatter-add + MFMA --------
// Pass A: 8 lanes/edge, lane fl scatters feats {fl+8j} via ds_add_f32 (+self as
// virtual edges). Pass B: h1 = relu(dinv*acc + b1) inline in A-frag; MFMA @ Wt2.
__global__ __launch_bounds__(256) void agg1gemm2_kernel(const unsigned short* __restrict__ t1,
                                                        const uint32* __restrict__ pairs,
                                                        const int* __restrict__ gcur,
                                                        const int* __restrict__ deg,
                                                        const float* __restrict__ b1,
                                                        const unsigned short* __restrict__ Wt2,
                                                        unsigned short* __restrict__ t2s) {
    __shared__ float h1acc[128 * 68];     // 34.8 KB, stride 68 (16B-aligned chunks)
    __shared__ uint32 spairs[BCAP];       // 12.3 KB; overlaid by Cs in Pass B
    __shared__ float ldv[128];
    __shared__ float lb1[64];
    unsigned short* Cs = (unsigned short*)spairs;   // 128*36*2 = 9216 B <= 12288

    int tid = threadIdx.x;
    int b = blockIdx.x;
    int node0 = b << 7;
    int cnt = gcur[b]; if (cnt > BCAP) cnt = BCAP;
    const uint32* pb = pairs + (size_t)b * BCAP;
    for (int k = tid; k < cnt; k += 256) spairs[k] = pb[k];
    for (int i = tid; i < 128 * 68; i += 256) h1acc[i] = 0.f;
    if (tid < 128) {
        int n = node0 + tid;
        ldv[tid] = (n < N_NODES) ? rsqrtf((float)(deg[n] + 1)) : 0.f;
    }
    if (tid < 64) lb1[tid] = b1[tid];
    __syncthreads();

    int lane = tid & 63, w = tid >> 6;
    int grp = lane >> 3, fl = lane & 7;         // 8 groups/wave, 8 lanes/group
    const uint4* t1q = (const uint4*)t1;
    int total = cnt + 128;                      // append 128 virtual self-edges
    int k0 = w * 8 + grp;
#define FETCH1(kk, vv, ll, oo) { oo = 0;                                          \
    if ((kk) < cnt) { uint32 pr = spairs[kk]; ll = (int)(pr >> 17);               \
        vv = t1q[(size_t)(pr & 0x1FFFF) * 8 + fl]; oo = 1; }                      \
    else if ((kk) < total) { ll = (kk) - cnt; int s_ = node0 + ll;                \
        if (s_ < N_NODES) { vv = t1q[(size_t)s_ * 8 + fl]; oo = 1; } } }
    uint4 v0 = make_uint4(0u, 0u, 0u, 0u); int ld0 = 0, ok0 = 0;
    FETCH1(k0, v0, ld0, ok0);
    for (int k = k0; k < total; k += 32) {
        uint4 v1 = make_uint4(0u, 0u, 0u, 0u); int ld1 = 0, ok1 = 0;
        FETCH1(k + 32, v1, ld1, ok1);
        if (ok0) {
            float* rr = &h1acc[ld0 * 68 + fl];  // feats fl+8j at word fl+8j
            atomicAdd(&rr[ 0], bflo(v0.x)); atomicAdd(&rr[ 8], bfhi(v0.x));
            atomicAdd(&rr[16], bflo(v0.y)); atomicAdd(&rr[24], bfhi(v0.y));
            atomicAdd(&rr[32], bflo(v0.z)); atomicAdd(&rr[40], bfhi(v0.z));
            atomicAdd(&rr[48], bflo(v0.w)); atomicAdd(&rr[56], bfhi(v0.w));
        }
        v0 = v1; ld0 = ld1; ok0 = ok1;
    }
#undef FETCH1
    __syncthreads();

    // ---- Pass B: gemm2 MFMA, M=128 (2 rowtiles/wave), K=64, N=32 ----
    int m = lane & 15, quad = lane >> 4;
    f32x4 acc[2][2];
#pragma unroll
    for (int i = 0; i < 2; i++)
#pragma unroll
        for (int j = 0; j < 2; j++) acc[i][j] = (f32x4){0.f, 0.f, 0.f, 0.f};
#pragma unroll
    for (int rt = 0; rt < 2; rt++) {
        int row = w * 32 + rt * 16 + m;
        float dvr = ldv[row];
#pragma unroll
        for (int ks = 0; ks < 2; ks++) {
            int kb = ks * 32 + quad * 8;
            const float* hp = &h1acc[row * 68 + kb];
            const float* bp = &lb1[kb];
            union { bf16x8 v; uint32 u[4]; } A;
            A.u[0] = pack2bf(fmaxf(fmaf(dvr, hp[0], bp[0]), 0.f),
                             fmaxf(fmaf(dvr, hp[1], bp[1]), 0.f));
            A.u[1] = pack2bf(fmaxf(fmaf(dvr, hp[2], bp[2]), 0.f),
                             fmaxf(fmaf(dvr, hp[3], bp[3]), 0.f));
            A.u[2] = pack2bf(fmaxf(fmaf(dvr, hp[4], bp[4]), 0.f),
                             fmaxf(fmaf(dvr, hp[5], bp[5]), 0.f));
            A.u[3] = pack2bf(fmaxf(fmaf(dvr, hp[6], bp[6]), 0.f),
                             fmaxf(fmaf(dvr, hp[7], bp[7]), 0.f));
            bf16x8 B0 = *(const bf16x8*)&Wt2[(0 * 16 + m) * HID_F + kb];
            bf16x8 B1 = *(const bf16x8*)&Wt2[(1 * 16 + m) * HID_F + kb];
            acc[rt][0] = __builtin_amdgcn_mfma_f32_16x16x32_bf16(A.v, B0, acc[rt][0], 0, 0, 0);
            acc[rt][1] = __builtin_amdgcn_mfma_f32_16x16x32_bf16(A.v, B1, acc[rt][1], 0, 0, 0);
        }
    }
    int cbase = 8 * (m & 3) + (m >> 2);   // xpose4 column for t2s; ntile adds +4*nt
#pragma unroll
    for (int rt = 0; rt < 2; rt++)
#pragma unroll
        for (int reg = 0; reg < 4; reg++) {
            int r = w * 32 + rt * 16 + quad * 4 + reg;
            float d = ldv[r];
            Cs[r * 36 + cbase + 0] = f2bf(acc[rt][0][reg] * d);
            Cs[r * 36 + cbase + 4] = f2bf(acc[rt][1][reg] * d);
        }
    __syncthreads();
#pragma unroll
    for (int it = 0; it < 4; it++) {
        int idx = it * 256 + tid;
        int r = idx >> 3, c = idx & 7;
        int nd = node0 + r;
        if (nd < N_NODES) {
            uint2 vv = *(const uint2*)&Cs[r * 36 + c * 4];
            *(uint2*)&t2s[(size_t)nd * Z_F + c * 4] = vv;
        }
    }
}

// ---------------- FUSED agg2+heads: per-bucket LDS f32 scatter-add + MFMA --------
// Pass A: 4 lanes/edge, lane f2 scatters feats {f2+4j}. Pass B: h2 = dinv*acc+b2
// inline; MFMA @ Wth (mu|lv), staged out via Sf (reuses h2acc).
__global__ __launch_bounds__(256) void agg2heads_kernel(const unsigned short* __restrict__ t2s,
                                                        const uint32* __restrict__ pairs,
                                                        const int* __restrict__ gcur,
                                                        const int* __restrict__ deg,
                                                        const float* __restrict__ b2,
                                                        const unsigned short* __restrict__ Wth,
                                                        const float* __restrict__ bmu,
                                                        const float* __restrict__ blv,
                                                        float* __restrict__ out) {
    __shared__ float h2acc[128 * 36];     // 18.4 KB; reused as out staging Sf
    __shared__ uint32 spairs[BCAP];
    __shared__ float ldv[128];
    __shared__ float lb2[32];
    __shared__ float lbm[32];
    __shared__ float lbl[32];

    int tid = threadIdx.x;
    int b = blockIdx.x;
    int node0 = b << 7;
    int cnt = gcur[b]; if (cnt > BCAP) cnt = BCAP;
    const uint32* pb = pairs + (size_t)b * BCAP;
    for (int k = tid; k < cnt; k += 256) spairs[k] = pb[k];
    for (int i = tid; i < 128 * 36; i += 256) h2acc[i] = 0.f;
    if (tid < 128) {
        int n = node0 + tid;
        ldv[tid] = (n < N_NODES) ? rsqrtf((float)(deg[n] + 1)) : 0.f;
    }
    if (tid < 32) { lb2[tid] = b2[tid]; lbm[tid] = bmu[tid]; lbl[tid] = blv[tid]; }
    __syncthreads();

    int lane = tid & 63, w = tid >> 6;
    int grp = lane >> 2, f2 = lane & 3;          // 16 groups/wave, 4 lanes/group
    const uint4* t2q = (const uint4*)t2s;
    int total = cnt + 128;
    int k0 = w * 16 + grp;
#define FETCH2(kk, vv, ll, oo) { oo = 0;                                          \
    if ((kk) < cnt) { uint32 pr = spairs[kk]; ll = (int)(pr >> 17);               \
        vv = t2q[(size_t)(pr & 0x1FFFF) * 4 + f2]; oo = 1; }                      \
    else if ((kk) < total) { ll = (kk) - cnt; int s_ = node0 + ll;                \
        if (s_ < N_NODES) { vv = t2q[(size_t)s_ * 4 + f2]; oo = 1; } } }
    uint4 v0 = make_uint4(0u, 0u, 0u, 0u); int ld0 = 0, ok0 = 0;
    FETCH2(k0, v0, ld0, ok0);
    for (int k = k0; k < total; k += 64) {
        uint4 v1 = make_uint4(0u, 0u, 0u, 0u); int ld1 = 0, ok1 = 0;
        FETCH2(k + 64, v1, ld1, ok1);
        if (ok0) {
            float* rr = &h2acc[ld0 * 36 + f2];  // feats f2+4j at word f2+4j
            atomicAdd(&rr[ 0], bflo(v0.x)); atomicAdd(&rr[ 4], bfhi(v0.x));
            atomicAdd(&rr[ 8], bflo(v0.y)); atomicAdd(&rr[12], bfhi(v0.y));
            atomicAdd(&rr[16], bflo(v0.z)); atomicAdd(&rr[20], bfhi(v0.z));
            atomicAdd(&rr[24], bflo(v0.w)); atomicAdd(&rr[28], bfhi(v0.w));
        }
        v0 = v1; ld0 = ld1; ok0 = ok1;
    }
#undef FETCH2
    __syncthreads();

    // ---- Pass B: heads MFMA, M=128 (2 rowtiles/wave), K=32, N=64 (mu|lv) ----
    int m = lane & 15, quad = lane >> 4;
    int kb = quad * 8;
    f32x4 acc[2][4];
#pragma unroll
    for (int i = 0; i < 2; i++)
#pragma unroll
        for (int j = 0; j < 4; j++) acc[i][j] = (f32x4){0.f, 0.f, 0.f, 0.f};
#pragma unroll
    for (int rt = 0; rt < 2; rt++) {
        int row = w * 32 + rt * 16 + m;
        float dvr = ldv[row];
        const float* hp = &h2acc[row * 36 + kb];
        const float* bp = &lb2[kb];
        union { bf16x8 v; uint32 u[4]; } A;
        A.u[0] = pack2bf(fmaf(dvr, hp[0], bp[0]), fmaf(dvr, hp[1], bp[1]));
        A.u[1] = pack2bf(fmaf(dvr, hp[2], bp[2]), fmaf(dvr, hp[3], bp[3]));
        A.u[2] = pack2bf(fmaf(dvr, hp[4], bp[4]), fmaf(dvr, hp[5], bp[5]));
        A.u[3] = pack2bf(fmaf(dvr, hp[6], bp[6]), fmaf(dvr, hp[7], bp[7]));
        bf16x8 B0 = *(const bf16x8*)&Wth[(0 * 16 + m) * Z_F + kb];
        bf16x8 B1 = *(const bf16x8*)&Wth[(1 * 16 + m) * Z_F + kb];
        bf16x8 B2 = *(const bf16x8*)&Wth[(2 * 16 + m) * Z_F + kb];
        bf16x8 B3 = *(const bf16x8*)&Wth[(3 * 16 + m) * Z_F + kb];
        acc[rt][0] = __builtin_amdgcn_mfma_f32_16x16x32_bf16(A.v, B0, acc[rt][0], 0, 0, 0);
        acc[rt][1] = __builtin_amdgcn_mfma_f32_16x16x32_bf16(A.v, B1, acc[rt][1], 0, 0, 0);
        acc[rt][2] = __builtin_amdgcn_mfma_f32_16x16x32_bf16(A.v, B2, acc[rt][2], 0, 0, 0);
        acc[rt][3] = __builtin_amdgcn_mfma_f32_16x16x32_bf16(A.v, B3, acc[rt][3], 0, 0, 0);
    }
    __syncthreads();                       // all h2acc reads done; reuse as Sf
    float* Sf = h2acc;
    // mu
#pragma unroll
    for (int rt = 0; rt < 2; rt++)
#pragma unroll
        for (int reg = 0; reg < 4; reg++) {
            int r = w * 32 + rt * 16 + quad * 4 + reg;
            Sf[r * 36 +  0 + m] = acc[rt][0][reg] + lbm[m];
            Sf[r * 36 + 16 + m] = acc[rt][1][reg] + lbm[16 + m];
        }
    __syncthreads();
#pragma unroll
    for (int it = 0; it < 4; it++) {
        int idx = it * 256 + tid;
        int r = idx >> 3, c = idx & 7;
        int nd = node0 + r;
        if (nd < N_NODES)
            *(float4*)&out[(size_t)nd * Z_F + c * 4] = *(const float4*)&Sf[r * 36 + c * 4];
    }
    __syncthreads();
    // lv
#pragma unroll
    for (int rt = 0; rt < 2; rt++)
#pragma unroll
        for (int reg = 0; reg < 4; reg++) {
            int r = w * 32 + rt * 16 + quad * 4 + reg;
            Sf[r * 36 +  0 + m] = acc[rt][2][reg] + lbl[m];
            Sf[r * 36 + 16 + m] = acc[rt][3][reg] + lbl[16 + m];
        }
    __syncthreads();
#pragma unroll
    for (int it = 0; it < 4; it++) {
        int idx = it * 256 + tid;
        int r = idx >> 3, c = idx & 7;
        int nd = node0 + r;
        if (nd < N_NODES)
            *(float4*)&out[(size_t)N_NODES * Z_F + (size_t)nd * Z_F + c * 4] =
                *(const float4*)&Sf[r * 36 + c * 4];
    }
}

extern "C" void kernel_launch(void* const* d_in, const int* in_sizes, int n_in,
                              void* d_out, int out_size, void* d_ws, size_t ws_size,
                              hipStream_t stream) {
    const float* x   = (const float*)d_in[0];
    const int*   ei  = (const int*)d_in[1];
    const float* W1  = (const float*)d_in[2];
    const float* b1  = (const float*)d_in[3];
    const float* W2  = (const float*)d_in[4];
    const float* b2  = (const float*)d_in[5];
    const float* Wmu = (const float*)d_in[6];
    const float* bmu = (const float*)d_in[7];
    const float* Wlv = (const float*)d_in[8];
    const float* blv = (const float*)d_in[9];
    float* out = (float*)d_out;

    char* ws = (char*)d_ws;
    size_t off = 0;
    auto A = [&](size_t bytes) {
        size_t r = off;
        off += (bytes + 255) & ~(size_t)255;
        return r;
    };
    int*   deg   = (int*)(ws + A((size_t)DEG_PAD * 4));   // 401,408 B (256B multiple)
    int*   gcur  = (int*)(ws + A((size_t)NBUK * 4));      // contiguous after deg
    unsigned short* Wt1 = (unsigned short*)(ws + A((size_t)IN_F * HID_F * 2));
    unsigned short* Wt2 = (unsigned short*)(ws + A((size_t)HID_F * Z_F * 2));
    unsigned short* Wth = (unsigned short*)(ws + A((size_t)Z_F * 64 * 2));
    uint32* pairs = (uint32*)(ws + A((size_t)NBUK * BCAP * 4));                   // 9.6 MB
    unsigned short* t1  = (unsigned short*)(ws + A((size_t)N_NODES * HID_F * 2)); // 12.8 MB
    unsigned short* t2s = (unsigned short*)(ws + A((size_t)N_NODES * Z_F * 2));   // 6.4 MB

    // zero deg + gcur in one contiguous memset
    hipMemsetAsync(deg, 0, (size_t)DEG_PAD * 4 + (size_t)NBUK * 4, stream);

    phase1_kernel<<<P1_BLOCKS + 1, 256, 0, stream>>>(ei, gcur, pairs, deg,
                                                     W1, W2, Wmu, Wlv, Wt1, Wt2, Wth);

    int nblk = (N_NODES + 63) / 64;   // 1563
    gemm1_kernel<<<nblk, 256, 0, stream>>>(x, Wt1, deg, t1);
    agg1gemm2_kernel<<<NBUK, 256, 0, stream>>>(t1, pairs, gcur, deg, b1, Wt2, t2s);
    agg2heads_kernel<<<NBUK, 256, 0, stream>>>(t2s, pairs, gcur, deg, b2, Wth, bmu, blv, out);
}

// Round 3
// 269.656 us; speedup vs baseline: 4.7627x; 4.7627x over previous
//
#include <hip/hip_runtime.h>

#define N_NODES 100000
#define N_EDGES 1600000
#define IN_F   128
#define HID_F  64
#define Z_F    32
#define NBUK   782          // ceil(100000/128) buckets of 128 dst nodes
#define BCAP   3072         // bucket capacity (mean 2046, sigma ~45)
#define P1T    8192         // edges per phase1 block (32/thread)
#define P1_BLOCKS ((N_EDGES + P1T - 1) / P1T)   // 196
#define AGG_CAP 2048        // LDS col capacity per 64-node block (mean 1024, +32 sigma)
#define DEG_PAD 100352      // N_NODES padded so DEG_PAD*4 is a 256B multiple
#define G1_BLOCKS ((N_NODES + 63) / 64)         // 1563

typedef unsigned int uint32;
typedef __attribute__((ext_vector_type(8))) short bf16x8;
typedef __attribute__((ext_vector_type(4))) float f32x4;

__device__ __forceinline__ unsigned short f2bf(float f) {
    unsigned u = __float_as_uint(f);
    u = (u + 0x7FFF + ((u >> 16) & 1)) >> 16;   // RNE
    return (unsigned short)u;
}
__device__ __forceinline__ uint32 pack2bf(float lo, float hi) {
    return (uint32)f2bf(lo) | ((uint32)f2bf(hi) << 16);
}
__device__ __forceinline__ float bflo(uint32 u) { return __uint_as_float(u << 16); }
__device__ __forceinline__ float bfhi(uint32 u) { return __uint_as_float(u & 0xFFFF0000u); }

#define ACC8(u) { a0 += bflo(u.x); a1 += bfhi(u.x); a2 += bflo(u.y); a3 += bfhi(u.y); \
                  a4 += bflo(u.z); a5 += bfhi(u.z); a6 += bflo(u.w); a7 += bfhi(u.w); }

// ---------------- phase 1: bucket partition + per-node degree; last block: weights
__global__ __launch_bounds__(256) void phase1_kernel(const int* __restrict__ ei,
                                                     int* __restrict__ gcur,
                                                     uint32* __restrict__ pairs,
                                                     int* __restrict__ deg,
                                                     const float* __restrict__ W1,
                                                     const float* __restrict__ W2,
                                                     const float* __restrict__ Wmu,
                                                     const float* __restrict__ Wlv,
                                                     unsigned short* __restrict__ Wt1,
                                                     unsigned short* __restrict__ Wt2,
                                                     unsigned short* __restrict__ Wth) {
    if (blockIdx.x == P1_BLOCKS) {   // weight transpose/convert block (no graph dep)
        int t = threadIdx.x;
        for (int i = t; i < IN_F * HID_F; i += 256) {        // Wt1[n][k] = W1[k][n]
            int n = i >> 7, k = i & 127;
            Wt1[i] = f2bf(W1[k * HID_F + n]);
        }
        for (int i = t; i < HID_F * Z_F; i += 256) {         // Wt2[n][k] = W2[k][n]
            int n = i >> 6, k = i & 63;
            Wt2[i] = f2bf(W2[k * Z_F + n]);
        }
        for (int i = t; i < Z_F * 64; i += 256) {            // Wth[n][k]: n<32 mu, else lv
            int n = i >> 5, k = i & 31;
            Wth[i] = f2bf(n < 32 ? Wmu[k * Z_F + n] : Wlv[k * Z_F + (n - 32)]);
        }
        return;
    }
    __shared__ int hist[NBUK];
    __shared__ int lbase[NBUK];
    __shared__ int gbase[NBUK];
    __shared__ int lcur[NBUK];
    __shared__ uint32 stage[P1T];
    __shared__ unsigned short sbid[P1T];
    __shared__ int part[256];
    int tid = threadIdx.x;
    int e0 = blockIdx.x * P1T;
    int ecnt = N_EDGES - e0; if (ecnt > P1T) ecnt = P1T;
    for (int b = tid; b < NBUK; b += 256) { hist[b] = 0; lcur[b] = 0; }
    __syncthreads();
    int myd[32];                      // dst cached in regs: read ei's dst half ONCE
#pragma unroll
    for (int i = 0; i < 32; i++) {
        int k = tid + i * 256;
        myd[i] = (k < ecnt) ? ei[N_EDGES + e0 + k] : -1;
    }
#pragma unroll
    for (int i = 0; i < 32; i++)
        if (myd[i] >= 0) {
            atomicAdd(&hist[myd[i] >> 7], 1);
            atomicAdd(&deg[myd[i]], 1);          // global per-node in-degree
        }
    __syncthreads();
    int t4 = tid * 4;
    int l0 = 0, l1 = 0, l2 = 0, l3 = 0, s = 0;
    if (t4 + 0 < NBUK) { l0 = hist[t4 + 0]; s += l0; }
    if (t4 + 1 < NBUK) { l1 = hist[t4 + 1]; s += l1; }
    if (t4 + 2 < NBUK) { l2 = hist[t4 + 2]; s += l2; }
    if (t4 + 3 < NBUK) { l3 = hist[t4 + 3]; s += l3; }
    part[tid] = s;
    __syncthreads();
    for (int off = 1; off < 256; off <<= 1) {
        int add = (tid >= off) ? part[tid - off] : 0;
        __syncthreads();
        part[tid] += add;
        __syncthreads();
    }
    int run = part[tid] - s;
    if (t4 + 0 < NBUK) { lbase[t4 + 0] = run; run += l0; }
    if (t4 + 1 < NBUK) { lbase[t4 + 1] = run; run += l1; }
    if (t4 + 2 < NBUK) { lbase[t4 + 2] = run; run += l2; }
    if (t4 + 3 < NBUK) { lbase[t4 + 3] = run; run += l3; }
    for (int b = tid; b < NBUK; b += 256) {
        int h = hist[b];
        gbase[b] = h ? atomicAdd(&gcur[b], h) : 0;
    }
    __syncthreads();
#pragma unroll
    for (int i = 0; i < 32; i++) {
        int k = tid + i * 256;
        if (k < ecnt) {
            int sN = ei[e0 + k];
            int d  = myd[i];
            int b = d >> 7;
            int slot = lbase[b] + atomicAdd(&lcur[b], 1);
            stage[slot] = (uint32)sN | ((uint32)(d & 127) << 17);
            sbid[slot] = (unsigned short)b;
        }
    }
    __syncthreads();
    for (int k = tid; k < ecnt; k += 256) {
        int b = sbid[k];
        int r = gbase[b] + (k - lbase[b]);
        if (r < BCAP) pairs[(size_t)b * BCAP + r] = stage[k];
    }
}

// ---------------- FUSED phase2 || gemm1 (data-independent, one launch) -----------
// blocks [0,NBUK): per-bucket CSR build (self-computed bucket prefix)
// blocks [NBUK, NBUK+G1_BLOCKS): t1 = bf16(rsqrt(deg+1) * (x@W1)) [N,64] via MFMA
__global__ __launch_bounds__(256) void p2g1_kernel(const uint32* __restrict__ pairs,
                                                   const int* __restrict__ gcur,
                                                   int* __restrict__ rowptr,
                                                   float* __restrict__ dinv,
                                                   int* __restrict__ col,
                                                   const float* __restrict__ x,
                                                   const unsigned short* __restrict__ Wt1,
                                                   const int* __restrict__ deg,
                                                   unsigned short* __restrict__ t1) {
    int tid = threadIdx.x;
    if (blockIdx.x < NBUK) {
        // ---------------- phase2 body ----------------
        __shared__ int lhist[128];
        __shared__ int lscan[128];
        __shared__ int lcur[128];
        __shared__ int stage[BCAP];
        __shared__ int wsum[4];
        int b = blockIdx.x;
        int cnt_b = gcur[b];
        if (cnt_b > BCAP) cnt_b = BCAP;
        // gbase = exclusive prefix sum of gcur over [0, b) — gcur is 3KB, L2-resident
        int partial = 0;
        for (int i = tid; i < b; i += 256) partial += gcur[i];
#pragma unroll
        for (int off = 32; off > 0; off >>= 1) partial += __shfl_down(partial, off);
        if (tid < 128) { lhist[tid] = 0; lcur[tid] = 0; }
        if ((tid & 63) == 0) wsum[tid >> 6] = partial;
        __syncthreads();
        int gbase = wsum[0] + wsum[1] + wsum[2] + wsum[3];
        int node0 = b << 7;
        int nb = N_NODES - node0;
        if (nb > 128) nb = 128;
        const uint32* pb = pairs + (size_t)b * BCAP;
        for (int k = tid; k < cnt_b; k += 256) atomicAdd(&lhist[pb[k] >> 17], 1);
        __syncthreads();
        int v = (tid < 128) ? lhist[tid] : 0;
        if (tid < 128) lscan[tid] = v;
        __syncthreads();
        for (int off = 1; off < 128; off <<= 1) {
            int add = (tid < 128 && tid >= off) ? lscan[tid - off] : 0;
            __syncthreads();
            if (tid < 128) lscan[tid] += add;
            __syncthreads();
        }
        if (tid < 128) lscan[tid] -= v;  // exclusive
        __syncthreads();
        if (tid < nb) {
            rowptr[node0 + tid] = gbase + lscan[tid];
            dinv[node0 + tid] = rsqrtf((float)(lhist[tid] + 1));
        }
        if (b == NBUK - 1 && tid == 0) rowptr[N_NODES] = N_EDGES;
        for (int k = tid; k < cnt_b; k += 256) {
            uint32 u = pb[k];
            int ld = u >> 17;
            int r = atomicAdd(&lcur[ld], 1);
            stage[lscan[ld] + r] = (int)(u & 0x1FFFF);
        }
        __syncthreads();
        for (int k = tid; k < cnt_b; k += 256) col[gbase + k] = stage[k];
        return;
    }
    // ---------------- gemm1 body ----------------
    __shared__ unsigned short Cs[64 * 72];
    __shared__ float dv[64];
    int node0 = (blockIdx.x - NBUK) * 64;
    if (tid < 64) {
        int n = node0 + tid;
        dv[tid] = (n < N_NODES) ? rsqrtf((float)(deg[n] + 1)) : 0.f;
    }
    __syncthreads();
    int w = tid >> 6, lane = tid & 63;
    int m = lane & 15, quad = lane >> 4;
    int row = w * 16 + m;
    int node = node0 + row;
    const float* xr = x + (size_t)min(node, N_NODES - 1) * IN_F;
    f32x4 acc0 = {0.f, 0.f, 0.f, 0.f};
    f32x4 acc1 = acc0, acc2 = acc0, acc3 = acc0;
#pragma unroll
    for (int ks = 0; ks < 4; ks++) {
        int kb = ks * 32 + quad * 8;
        float4 f0 = *(const float4*)(xr + kb);
        float4 f1 = *(const float4*)(xr + kb + 4);
        union { bf16x8 v; unsigned short u[8]; } A;
        A.u[0] = f2bf(f0.x); A.u[1] = f2bf(f0.y); A.u[2] = f2bf(f0.z); A.u[3] = f2bf(f0.w);
        A.u[4] = f2bf(f1.x); A.u[5] = f2bf(f1.y); A.u[6] = f2bf(f1.z); A.u[7] = f2bf(f1.w);
        bf16x8 b0 = *(const bf16x8*)&Wt1[(0 * 16 + m) * IN_F + kb];
        bf16x8 b1 = *(const bf16x8*)&Wt1[(1 * 16 + m) * IN_F + kb];
        bf16x8 b2 = *(const bf16x8*)&Wt1[(2 * 16 + m) * IN_F + kb];
        bf16x8 b3 = *(const bf16x8*)&Wt1[(3 * 16 + m) * IN_F + kb];
        acc0 = __builtin_amdgcn_mfma_f32_16x16x32_bf16(A.v, b0, acc0, 0, 0, 0);
        acc1 = __builtin_amdgcn_mfma_f32_16x16x32_bf16(A.v, b1, acc1, 0, 0, 0);
        acc2 = __builtin_amdgcn_mfma_f32_16x16x32_bf16(A.v, b2, acc2, 0, 0, 0);
        acc3 = __builtin_amdgcn_mfma_f32_16x16x32_bf16(A.v, b3, acc3, 0, 0, 0);
    }
    int rbase = w * 16 + quad * 4;
#pragma unroll
    for (int reg = 0; reg < 4; reg++) {
        int r = rbase + reg;
        float d = dv[r];
        Cs[r * 72 +  0 + m] = f2bf(acc0[reg] * d);
        Cs[r * 72 + 16 + m] = f2bf(acc1[reg] * d);
        Cs[r * 72 + 32 + m] = f2bf(acc2[reg] * d);
        Cs[r * 72 + 48 + m] = f2bf(acc3[reg] * d);
    }
    __syncthreads();
#pragma unroll
    for (int it = 0; it < 4; it++) {
        int idx = it * 256 + tid;
        int r = idx >> 4, c = idx & 15;
        int nd = node0 + r;
        if (nd < N_NODES) {
            uint2 vv = *(const uint2*)&Cs[r * 72 + c * 4];
            *(uint2*)&t1[(size_t)nd * HID_F + c * 4] = vv;
        }
    }
}

// ---------------- FUSED agg1+gemm2: h1 lives in LDS only; emits t2s --------------
// Phase A (agg1): 8-lane group = node, lane fl holds feats 8fl..8fl+7 (uint4 gather).
// Phase B (gemm2): MFMA h1s @ Wt2 -> t2s = bf16(dinv * (h1@W2)).
__global__ __launch_bounds__(256) void agg1gemm2_kernel(const unsigned short* __restrict__ t1,
                                                        const int* __restrict__ rowptr,
                                                        const int* __restrict__ col,
                                                        const float* __restrict__ dinv,
                                                        const float* __restrict__ b1,
                                                        const unsigned short* __restrict__ Wt2,
                                                        unsigned short* __restrict__ t2s) {
    __shared__ int lcol[AGG_CAP];
    __shared__ int lrp[65];
    __shared__ float ldv[64];
    __shared__ unsigned short h1s[64 * 72];   // bf16 h1 tile, row stride 72 shorts
    __shared__ unsigned short Cs[64 * 36];    // t2s staging
    int tid = threadIdx.x;
    int node0 = blockIdx.x * 64;
    if (tid < 65) lrp[tid] = rowptr[min(node0 + tid, N_NODES)];
    __syncthreads();
    int s0 = lrp[0];
    int cnt = lrp[64] - s0; if (cnt > AGG_CAP) cnt = AGG_CAP;
    for (int k = tid; k < cnt; k += 256) lcol[k] = col[s0 + k];
    if (tid < 64) {
        int n = node0 + tid;
        ldv[tid] = (n < N_NODES) ? dinv[n] : 0.f;
    }
    __syncthreads();
    int lane = tid & 63, w = tid >> 6;
    int grp = lane >> 3, fl = lane & 7;    // 8 groups/wave, 8 lanes/group (16B each)
    int gg = w * 8 + grp;                  // 0..31
    const uint4* t1q = (const uint4*)t1;   // row stride 8 uint4 (128B)
    float4 bb0 = ((const float4*)b1)[fl * 2];
    float4 bb1 = ((const float4*)b1)[fl * 2 + 1];
#pragma unroll
    for (int rep = 0; rep < 2; rep++) {
        int li = gg + rep * 32;
        int node = node0 + li;
        uint4 pk = make_uint4(0u, 0u, 0u, 0u);
        if (node < N_NODES) {
            int s = lrp[li] - s0;
            int e = lrp[li + 1] - s0; if (e > cnt) e = cnt;
            float a0 = 0.f, a1 = 0.f, a2 = 0.f, a3 = 0.f;
            float a4 = 0.f, a5 = 0.f, a6 = 0.f, a7 = 0.f;
            int p = s;
            for (; p + 3 < e; p += 4) {
                int c0 = lcol[p], c1 = lcol[p + 1], c2 = lcol[p + 2], c3 = lcol[p + 3];
                uint4 u0 = t1q[(size_t)c0 * 8 + fl];
                uint4 u1 = t1q[(size_t)c1 * 8 + fl];
                uint4 u2 = t1q[(size_t)c2 * 8 + fl];
                uint4 u3 = t1q[(size_t)c3 * 8 + fl];
                ACC8(u0); ACC8(u1); ACC8(u2); ACC8(u3);
            }
            for (; p < e; p++) {
                uint4 u = t1q[(size_t)lcol[p] * 8 + fl];
                ACC8(u);
            }
            uint4 us = t1q[(size_t)node * 8 + fl];   // self (already dinv-scaled)
            float di = ldv[li];
            float o0 = fmaxf(di * (a0 + bflo(us.x)) + bb0.x, 0.f);
            float o1 = fmaxf(di * (a1 + bfhi(us.x)) + bb0.y, 0.f);
            float o2 = fmaxf(di * (a2 + bflo(us.y)) + bb0.z, 0.f);
            float o3 = fmaxf(di * (a3 + bfhi(us.y)) + bb0.w, 0.f);
            float o4 = fmaxf(di * (a4 + bflo(us.z)) + bb1.x, 0.f);
            float o5 = fmaxf(di * (a5 + bfhi(us.z)) + bb1.y, 0.f);
            float o6 = fmaxf(di * (a6 + bflo(us.w)) + bb1.z, 0.f);
            float o7 = fmaxf(di * (a7 + bfhi(us.w)) + bb1.w, 0.f);
            pk.x = pack2bf(o0, o1);
            pk.y = pack2bf(o2, o3);
            pk.z = pack2bf(o4, o5);
            pk.w = pack2bf(o6, o7);
        }
        *(uint4*)&h1s[li * 72 + fl * 8] = pk;
    }
    __syncthreads();
    // ---- gemm2 MFMA: K=64 (2 steps), N=32 (2 tiles) ----
    int m = lane & 15, quad = lane >> 4;
    int row = w * 16 + m;
    f32x4 acc0 = {0.f, 0.f, 0.f, 0.f};
    f32x4 acc1 = acc0;
#pragma unroll
    for (int ks = 0; ks < 2; ks++) {
        int kb = ks * 32 + quad * 8;
        bf16x8 a  = *(const bf16x8*)&h1s[row * 72 + kb];
        bf16x8 b0 = *(const bf16x8*)&Wt2[(0 * 16 + m) * HID_F + kb];
        bf16x8 b1v = *(const bf16x8*)&Wt2[(1 * 16 + m) * HID_F + kb];
        acc0 = __builtin_amdgcn_mfma_f32_16x16x32_bf16(a, b0, acc0, 0, 0, 0);
        acc1 = __builtin_amdgcn_mfma_f32_16x16x32_bf16(a, b1v, acc1, 0, 0, 0);
    }
    int rbase = w * 16 + quad * 4;
#pragma unroll
    for (int reg = 0; reg < 4; reg++) {
        int r = rbase + reg;
        float d = ldv[r];
        Cs[r * 36 +  0 + m] = f2bf(acc0[reg] * d);
        Cs[r * 36 + 16 + m] = f2bf(acc1[reg] * d);
    }
    __syncthreads();
#pragma unroll
    for (int it = 0; it < 2; it++) {
        int idx = it * 256 + tid;
        int r = idx >> 3, c = idx & 7;
        int nd = node0 + r;
        if (nd < N_NODES) {
            uint2 vv = *(const uint2*)&Cs[r * 36 + c * 4];
            *(uint2*)&t2s[(size_t)nd * Z_F + c * 4] = vv;
        }
    }
}

// ---------------- FUSED agg2+heads: h2 lives in LDS only; emits out --------------
// Phase A (agg2): 4-lane group = node, lane fo holds feats 8fo..8fo+7 (uint4 gather).
// Phase B (heads): MFMA h2s @ Wth(+bias) -> out [mu|lv].
__global__ __launch_bounds__(256) void agg2heads_kernel(const unsigned short* __restrict__ t2s,
                                                        const int* __restrict__ rowptr,
                                                        const int* __restrict__ col,
                                                        const float* __restrict__ dinv,
                                                        const float* __restrict__ b2,
                                                        const unsigned short* __restrict__ Wth,
                                                        const float* __restrict__ bmu,
                                                        const float* __restrict__ blv,
                                                        float* __restrict__ out) {
    __shared__ int lcol[AGG_CAP];
    __shared__ int lrp[65];
    __shared__ float ldv[64];
    __shared__ unsigned short h2s[64 * 40];   // bf16 h2 tile, row stride 40 shorts
    __shared__ float Cf[64 * 68];             // out staging
    __shared__ float bias[64];
    int tid = threadIdx.x;
    int node0 = blockIdx.x * 64;
    if (tid < 65) lrp[tid] = rowptr[min(node0 + tid, N_NODES)];
    else if (tid >= 96 && tid < 128) bias[tid - 96] = bmu[tid - 96];
    else if (tid >= 128 && tid < 160) bias[tid - 96] = blv[tid - 128];
    __syncthreads();
    int s0 = lrp[0];
    int cnt = lrp[64] - s0; if (cnt > AGG_CAP) cnt = AGG_CAP;
    for (int k = tid; k < cnt; k += 256) lcol[k] = col[s0 + k];
    if (tid < 64) {
        int n = node0 + tid;
        ldv[tid] = (n < N_NODES) ? dinv[n] : 0.f;
    }
    __syncthreads();
    int lane = tid & 63, w = tid >> 6;
    int grp = lane >> 2, fo = lane & 3;    // 16 groups/wave, 4 lanes/group (16B each)
    int li = w * 16 + grp;                 // 0..63, single rep
    const uint4* t2q = (const uint4*)t2s;  // row stride 4 uint4 (64B)
    float4 bb0 = ((const float4*)b2)[fo * 2];
    float4 bb1 = ((const float4*)b2)[fo * 2 + 1];
    {
        int node = node0 + li;
        uint4 pk = make_uint4(0u, 0u, 0u, 0u);
        if (node < N_NODES) {
            int s = lrp[li] - s0;
            int e = lrp[li + 1] - s0; if (e > cnt) e = cnt;
            float a0 = 0.f, a1 = 0.f, a2 = 0.f, a3 = 0.f;
            float a4 = 0.f, a5 = 0.f, a6 = 0.f, a7 = 0.f;
            int p = s;
            for (; p + 3 < e; p += 4) {
                int c0 = lcol[p], c1 = lcol[p + 1], c2 = lcol[p + 2], c3 = lcol[p + 3];
                uint4 u0 = t2q[(size_t)c0 * 4 + fo];
                uint4 u1 = t2q[(size_t)c1 * 4 + fo];
                uint4 u2 = t2q[(size_t)c2 * 4 + fo];
                uint4 u3 = t2q[(size_t)c3 * 4 + fo];
                ACC8(u0); ACC8(u1); ACC8(u2); ACC8(u3);
            }
            for (; p < e; p++) {
                uint4 u = t2q[(size_t)lcol[p] * 4 + fo];
                ACC8(u);
            }
            uint4 us = t2q[(size_t)node * 4 + fo];
            float di = ldv[li];
            float o0 = di * (a0 + bflo(us.x)) + bb0.x;
            float o1 = di * (a1 + bfhi(us.x)) + bb0.y;
            float o2 = di * (a2 + bflo(us.y)) + bb0.z;
            float o3 = di * (a3 + bfhi(us.y)) + bb0.w;
            float o4 = di * (a4 + bflo(us.z)) + bb1.x;
            float o5 = di * (a5 + bfhi(us.z)) + bb1.y;
            float o6 = di * (a6 + bflo(us.w)) + bb1.z;
            float o7 = di * (a7 + bfhi(us.w)) + bb1.w;
            pk.x = pack2bf(o0, o1);
            pk.y = pack2bf(o2, o3);
            pk.z = pack2bf(o4, o5);
            pk.w = pack2bf(o6, o7);
        }
        *(uint4*)&h2s[li * 40 + fo * 8] = pk;
    }
    __syncthreads();
    // ---- heads MFMA: K=32 (1 step), N=64 (4 tiles: mu 0-31, lv 32-63) ----
    int m = lane & 15, quad = lane >> 4;
    int row = w * 16 + m;
    int kb = quad * 8;
    bf16x8 a  = *(const bf16x8*)&h2s[row * 40 + kb];
    bf16x8 b0 = *(const bf16x8*)&Wth[(0 * 16 + m) * Z_F + kb];
    bf16x8 b1 = *(const bf16x8*)&Wth[(1 * 16 + m) * Z_F + kb];
    bf16x8 b2v = *(const bf16x8*)&Wth[(2 * 16 + m) * Z_F + kb];
    bf16x8 b3 = *(const bf16x8*)&Wth[(3 * 16 + m) * Z_F + kb];
    f32x4 acc0 = {0.f, 0.f, 0.f, 0.f};
    f32x4 acc1 = acc0, acc2 = acc0, acc3 = acc0;
    acc0 = __builtin_amdgcn_mfma_f32_16x16x32_bf16(a, b0, acc0, 0, 0, 0);
    acc1 = __builtin_amdgcn_mfma_f32_16x16x32_bf16(a, b1, acc1, 0, 0, 0);
    acc2 = __builtin_amdgcn_mfma_f32_16x16x32_bf16(a, b2v, acc2, 0, 0, 0);
    acc3 = __builtin_amdgcn_mfma_f32_16x16x32_bf16(a, b3, acc3, 0, 0, 0);
    int rbase = w * 16 + quad * 4;
#pragma unroll
    for (int reg = 0; reg < 4; reg++) {
        int r = rbase + reg;
        Cf[r * 68 +  0 + m] = acc0[reg] + bias[ 0 + m];
        Cf[r * 68 + 16 + m] = acc1[reg] + bias[16 + m];
        Cf[r * 68 + 32 + m] = acc2[reg] + bias[32 + m];
        Cf[r * 68 + 48 + m] = acc3[reg] + bias[48 + m];
    }
    __syncthreads();
#pragma unroll
    for (int it = 0; it < 2; it++) {
        int idx = it * 256 + tid;
        int r = idx >> 3, c = idx & 7;
        int nd = node0 + r;
        if (nd < N_NODES) {
            float4 vmu = *(const float4*)&Cf[r * 68 + c * 4];
            float4 vlv = *(const float4*)&Cf[r * 68 + 32 + c * 4];
            *(float4*)&out[(size_t)nd * Z_F + c * 4] = vmu;
            *(float4*)&out[(size_t)N_NODES * Z_F + (size_t)nd * Z_F + c * 4] = vlv;
        }
    }
}

extern "C" void kernel_launch(void* const* d_in, const int* in_sizes, int n_in,
                              void* d_out, int out_size, void* d_ws, size_t ws_size,
                              hipStream_t stream) {
    const float* x   = (const float*)d_in[0];
    const int*   ei  = (const int*)d_in[1];
    const float* W1  = (const float*)d_in[2];
    const float* b1  = (const float*)d_in[3];
    const float* W2  = (const float*)d_in[4];
    const float* b2  = (const float*)d_in[5];
    const float* Wmu = (const float*)d_in[6];
    const float* bmu = (const float*)d_in[7];
    const float* Wlv = (const float*)d_in[8];
    const float* blv = (const float*)d_in[9];
    float* out = (float*)d_out;

    char* ws = (char*)d_ws;
    size_t off = 0;
    auto A = [&](size_t bytes) {
        size_t r = off;
        off += (bytes + 255) & ~(size_t)255;
        return r;
    };
    int*   deg   = (int*)(ws + A((size_t)DEG_PAD * 4));   // 401,408 B (256B multiple)
    int*   gcur  = (int*)(ws + A((size_t)NBUK * 4));      // contiguous after deg
    int*   rowptr = (int*)(ws + A((size_t)(N_NODES + 1) * 4));
    float* dinv   = (float*)(ws + A((size_t)N_NODES * 4));
    unsigned short* Wt1 = (unsigned short*)(ws + A((size_t)IN_F * HID_F * 2));
    unsigned short* Wt2 = (unsigned short*)(ws + A((size_t)HID_F * Z_F * 2));
    unsigned short* Wth = (unsigned short*)(ws + A((size_t)Z_F * 64 * 2));
    int*   col        = (int*)(ws + A((size_t)N_EDGES * 4));                    // 6.4 MB
    char*  reg1 = ws + A((size_t)NBUK * BCAP * 4);                              // 9.6 MB: pairs -> t2s
    uint32* pairs = (uint32*)reg1;                // dead after p2g1 (phase2 part)
    unsigned short* t2s = (unsigned short*)reg1;  // 6.4 MB, written by agg1gemm2
    unsigned short* t1 = (unsigned short*)(ws + A((size_t)N_NODES * HID_F * 2)); // 12.8 MB

    // zero deg + gcur in one contiguous memset
    hipMemsetAsync(deg, 0, (size_t)DEG_PAD * 4 + (size_t)NBUK * 4, stream);

    phase1_kernel<<<P1_BLOCKS + 1, 256, 0, stream>>>(ei, gcur, pairs, deg,
                                                     W1, W2, Wmu, Wlv, Wt1, Wt2, Wth);
    p2g1_kernel<<<NBUK + G1_BLOCKS, 256, 0, stream>>>(pairs, gcur, rowptr, dinv, col,
                                                      x, Wt1, deg, t1);
    agg1gemm2_kernel<<<G1_BLOCKS, 256, 0, stream>>>(t1, rowptr, col, dinv, b1, Wt2, t2s);
    agg2heads_kernel<<<G1_BLOCKS, 256, 0, stream>>>(t2s, rowptr, col, dinv, b2, Wth, bmu, blv, out);
}

// Round 4
// 210.571 us; speedup vs baseline: 6.0991x; 1.2806x over previous
//
#include <hip/hip_runtime.h>

#define N_NODES 100000
#define N_EDGES 1600000
#define IN_F   128
#define HID_F  64
#define Z_F    32
#define NBUK   782          // ceil(100000/128) buckets of 128 dst nodes
#define BCAP   3072         // bucket capacity (mean 2046, sigma ~45)
#define P1T    4096         // edges per phase1 block (8/thread at 512 threads)
#define P1_BLOCKS ((N_EDGES + P1T - 1) / P1T)   // 391
#define AGG_CAP 2048        // LDS col capacity per 64-node block (mean 1024, +32 sigma)
#define G1_BLOCKS ((N_NODES + 63) / 64)         // 1563

typedef unsigned int uint32;
typedef __attribute__((ext_vector_type(8))) short bf16x8;
typedef __attribute__((ext_vector_type(4))) float f32x4;

__device__ __forceinline__ unsigned short f2bf(float f) {
    unsigned u = __float_as_uint(f);
    u = (u + 0x7FFF + ((u >> 16) & 1)) >> 16;   // RNE
    return (unsigned short)u;
}
__device__ __forceinline__ uint32 pack2bf(float lo, float hi) {
    return (uint32)f2bf(lo) | ((uint32)f2bf(hi) << 16);
}
__device__ __forceinline__ float bflo(uint32 u) { return __uint_as_float(u << 16); }
__device__ __forceinline__ float bfhi(uint32 u) { return __uint_as_float(u & 0xFFFF0000u); }

#define ACC8(u) { a0 += bflo(u.x); a1 += bfhi(u.x); a2 += bflo(u.y); a3 += bfhi(u.y); \
                  a4 += bflo(u.z); a5 += bfhi(u.z); a6 += bflo(u.w); a7 += bfhi(u.w); }

// ---------------- phase 1: bucket partition (512 thr for TLP); last blk: weights --
__global__ __launch_bounds__(512) void phase1_kernel(const int* __restrict__ ei,
                                                     int* __restrict__ gcur,
                                                     uint32* __restrict__ pairs,
                                                     const float* __restrict__ W1,
                                                     const float* __restrict__ W2,
                                                     const float* __restrict__ Wmu,
                                                     const float* __restrict__ Wlv,
                                                     unsigned short* __restrict__ Wt1,
                                                     unsigned short* __restrict__ Wt2,
                                                     unsigned short* __restrict__ Wth) {
    if (blockIdx.x == P1_BLOCKS) {   // weight transpose/convert block (no graph dep)
        int t = threadIdx.x;
        for (int i = t; i < IN_F * HID_F; i += 512) {        // Wt1[n][k] = W1[k][n]
            int n = i >> 7, k = i & 127;
            Wt1[i] = f2bf(W1[k * HID_F + n]);
        }
        for (int i = t; i < HID_F * Z_F; i += 512) {         // Wt2[n][k] = W2[k][n]
            int n = i >> 6, k = i & 63;
            Wt2[i] = f2bf(W2[k * Z_F + n]);
        }
        for (int i = t; i < Z_F * 64; i += 512) {            // Wth[n][k]: n<32 mu, else lv
            int n = i >> 5, k = i & 31;
            Wth[i] = f2bf(n < 32 ? Wmu[k * Z_F + n] : Wlv[k * Z_F + (n - 32)]);
        }
        return;
    }
    __shared__ int hist[NBUK];
    __shared__ int lbase[NBUK];
    __shared__ int gbase[NBUK];
    __shared__ int lcur[NBUK];
    __shared__ uint32 stage[P1T];
    __shared__ unsigned short sbid[P1T];
    __shared__ int part[512];
    int tid = threadIdx.x;
    int e0 = blockIdx.x * P1T;
    int ecnt = N_EDGES - e0; if (ecnt > P1T) ecnt = P1T;
    for (int b = tid; b < NBUK; b += 512) { hist[b] = 0; lcur[b] = 0; }
    __syncthreads();
    int myd[8];                       // dst cached in regs: read ei's dst half ONCE
#pragma unroll
    for (int i = 0; i < 8; i++) {
        int k = tid + i * 512;
        myd[i] = (k < ecnt) ? ei[N_EDGES + e0 + k] : -1;
    }
#pragma unroll
    for (int i = 0; i < 8; i++)
        if (myd[i] >= 0) atomicAdd(&hist[myd[i] >> 7], 1);
    __syncthreads();
    int t2 = tid * 2;
    int l0 = 0, l1 = 0, s = 0;
    if (t2 + 0 < NBUK) { l0 = hist[t2 + 0]; s += l0; }
    if (t2 + 1 < NBUK) { l1 = hist[t2 + 1]; s += l1; }
    part[tid] = s;
    __syncthreads();
    for (int off = 1; off < 512; off <<= 1) {
        int add = (tid >= off) ? part[tid - off] : 0;
        __syncthreads();
        part[tid] += add;
        __syncthreads();
    }
    int run = part[tid] - s;
    if (t2 + 0 < NBUK) { lbase[t2 + 0] = run; run += l0; }
    if (t2 + 1 < NBUK) { lbase[t2 + 1] = run; }
    for (int b = tid; b < NBUK; b += 512) {
        int h = hist[b];
        gbase[b] = h ? atomicAdd(&gcur[b], h) : 0;
    }
    __syncthreads();
#pragma unroll
    for (int i = 0; i < 8; i++) {
        int k = tid + i * 512;
        if (k < ecnt) {
            int sN = ei[e0 + k];
            int d  = myd[i];
            int b = d >> 7;
            int slot = lbase[b] + atomicAdd(&lcur[b], 1);
            stage[slot] = (uint32)sN | ((uint32)(d & 127) << 17);
            sbid[slot] = (unsigned short)b;
        }
    }
    __syncthreads();
    for (int k = tid; k < ecnt; k += 512) {
        int b = sbid[k];
        int r = gbase[b] + (k - lbase[k < ecnt ? b : 0]);
        // (b is always valid here; expression kept simple)
        r = gbase[b] + (k - lbase[b]);
        if (r < BCAP) pairs[(size_t)b * BCAP + r] = stage[k];
    }
}

// ---------------- FUSED phase2 || gemm1 (both depend only on phase1) -------------
// blocks [0,NBUK): per-bucket CSR build (self-computed bucket prefix) + dinv
// blocks [NBUK, NBUK+G1_BLOCKS): gemm1 with SELF-COMPUTED dinv (bucket histogram)
__global__ __launch_bounds__(256) void p2g1_kernel(const uint32* __restrict__ pairs,
                                                   const int* __restrict__ gcur,
                                                   int* __restrict__ rowptr,
                                                   float* __restrict__ dinv,
                                                   int* __restrict__ col,
                                                   const float* __restrict__ x,
                                                   const unsigned short* __restrict__ Wt1,
                                                   unsigned short* __restrict__ t1) {
    int tid = threadIdx.x;
    if (blockIdx.x < NBUK) {
        // ---------------- phase2 body ----------------
        __shared__ int lhist[128];
        __shared__ int lscan[128];
        __shared__ int lcur[128];
        __shared__ int stage[BCAP];
        __shared__ int wsum[4];
        int b = blockIdx.x;
        int cnt_b = gcur[b];
        if (cnt_b > BCAP) cnt_b = BCAP;
        // gbase = exclusive prefix sum of gcur over [0, b) — gcur is 3KB, L2-resident
        int partial = 0;
        for (int i = tid; i < b; i += 256) partial += gcur[i];
#pragma unroll
        for (int off = 32; off > 0; off >>= 1) partial += __shfl_down(partial, off);
        if (tid < 128) { lhist[tid] = 0; lcur[tid] = 0; }
        if ((tid & 63) == 0) wsum[tid >> 6] = partial;
        __syncthreads();
        int gbase = wsum[0] + wsum[1] + wsum[2] + wsum[3];
        int node0 = b << 7;
        int nb = N_NODES - node0;
        if (nb > 128) nb = 128;
        const uint32* pb = pairs + (size_t)b * BCAP;
        for (int k = tid; k < cnt_b; k += 256) atomicAdd(&lhist[pb[k] >> 17], 1);
        __syncthreads();
        int v = (tid < 128) ? lhist[tid] : 0;
        if (tid < 128) lscan[tid] = v;
        __syncthreads();
        for (int off = 1; off < 128; off <<= 1) {
            int add = (tid < 128 && tid >= off) ? lscan[tid - off] : 0;
            __syncthreads();
            if (tid < 128) lscan[tid] += add;
            __syncthreads();
        }
        if (tid < 128) lscan[tid] -= v;  // exclusive
        __syncthreads();
        if (tid < nb) {
            rowptr[node0 + tid] = gbase + lscan[tid];
            dinv[node0 + tid] = rsqrtf((float)(lhist[tid] + 1));
        }
        if (b == NBUK - 1 && tid == 0) rowptr[N_NODES] = N_EDGES;
        for (int k = tid; k < cnt_b; k += 256) {
            uint32 u = pb[k];
            int ld = u >> 17;
            int r = atomicAdd(&lcur[ld], 1);
            stage[lscan[ld] + r] = (int)(u & 0x1FFFF);
        }
        __syncthreads();
        for (int k = tid; k < cnt_b; k += 256) col[gbase + k] = stage[k];
        return;
    }
    // ---------------- gemm1 body (self-computed dinv from pairs histogram) -------
    __shared__ unsigned short Cs[64 * 72];
    __shared__ float dv[64];
    __shared__ int h64[64];
    int g = blockIdx.x - NBUK;
    int node0 = g * 64;
    int bk = node0 >> 7, half = (node0 >> 6) & 1;
    int cnt_b = gcur[bk];
    if (cnt_b > BCAP) cnt_b = BCAP;
    if (tid < 64) h64[tid] = 0;
    __syncthreads();
    const uint32* pb = pairs + (size_t)bk * BCAP;
    for (int k = tid; k < cnt_b; k += 256) {
        int ld = pb[k] >> 17;
        if ((ld >> 6) == half) atomicAdd(&h64[ld & 63], 1);
    }
    __syncthreads();
    if (tid < 64) {
        int n = node0 + tid;
        dv[tid] = (n < N_NODES) ? rsqrtf((float)(h64[tid] + 1)) : 0.f;
    }
    __syncthreads();
    int w = tid >> 6, lane = tid & 63;
    int m = lane & 15, quad = lane >> 4;
    int row = w * 16 + m;
    int node = node0 + row;
    const float* xr = x + (size_t)min(node, N_NODES - 1) * IN_F;
    f32x4 acc0 = {0.f, 0.f, 0.f, 0.f};
    f32x4 acc1 = acc0, acc2 = acc0, acc3 = acc0;
#pragma unroll
    for (int ks = 0; ks < 4; ks++) {
        int kb = ks * 32 + quad * 8;
        float4 f0 = *(const float4*)(xr + kb);
        float4 f1 = *(const float4*)(xr + kb + 4);
        union { bf16x8 v; unsigned short u[8]; } A;
        A.u[0] = f2bf(f0.x); A.u[1] = f2bf(f0.y); A.u[2] = f2bf(f0.z); A.u[3] = f2bf(f0.w);
        A.u[4] = f2bf(f1.x); A.u[5] = f2bf(f1.y); A.u[6] = f2bf(f1.z); A.u[7] = f2bf(f1.w);
        bf16x8 b0 = *(const bf16x8*)&Wt1[(0 * 16 + m) * IN_F + kb];
        bf16x8 b1 = *(const bf16x8*)&Wt1[(1 * 16 + m) * IN_F + kb];
        bf16x8 b2 = *(const bf16x8*)&Wt1[(2 * 16 + m) * IN_F + kb];
        bf16x8 b3 = *(const bf16x8*)&Wt1[(3 * 16 + m) * IN_F + kb];
        acc0 = __builtin_amdgcn_mfma_f32_16x16x32_bf16(A.v, b0, acc0, 0, 0, 0);
        acc1 = __builtin_amdgcn_mfma_f32_16x16x32_bf16(A.v, b1, acc1, 0, 0, 0);
        acc2 = __builtin_amdgcn_mfma_f32_16x16x32_bf16(A.v, b2, acc2, 0, 0, 0);
        acc3 = __builtin_amdgcn_mfma_f32_16x16x32_bf16(A.v, b3, acc3, 0, 0, 0);
    }
    int rbase = w * 16 + quad * 4;
#pragma unroll
    for (int reg = 0; reg < 4; reg++) {
        int r = rbase + reg;
        float d = dv[r];
        Cs[r * 72 +  0 + m] = f2bf(acc0[reg] * d);
        Cs[r * 72 + 16 + m] = f2bf(acc1[reg] * d);
        Cs[r * 72 + 32 + m] = f2bf(acc2[reg] * d);
        Cs[r * 72 + 48 + m] = f2bf(acc3[reg] * d);
    }
    __syncthreads();
#pragma unroll
    for (int it = 0; it < 4; it++) {
        int idx = it * 256 + tid;
        int r = idx >> 4, c = idx & 15;
        int nd = node0 + r;
        if (nd < N_NODES) {
            uint2 vv = *(const uint2*)&Cs[r * 72 + c * 4];
            *(uint2*)&t1[(size_t)nd * HID_F + c * 4] = vv;
        }
    }
}

// ---------------- FUSED agg1+gemm2: h1 lives in LDS only; emits t2s --------------
// Phase A (agg1): 8-lane group = node, lane fl holds feats 8fl..8fl+7 (uint4 gather).
// Phase B (gemm2): MFMA h1s @ Wt2 -> t2s = bf16(dinv * (h1@W2)).
__global__ __launch_bounds__(256) void agg1gemm2_kernel(const unsigned short* __restrict__ t1,
                                                        const int* __restrict__ rowptr,
                                                        const int* __restrict__ col,
                                                        const float* __restrict__ dinv,
                                                        const float* __restrict__ b1,
                                                        const unsigned short* __restrict__ Wt2,
                                                        unsigned short* __restrict__ t2s) {
    __shared__ int lcol[AGG_CAP];
    __shared__ int lrp[65];
    __shared__ float ldv[64];
    __shared__ unsigned short h1s[64 * 72];   // bf16 h1 tile, row stride 72 shorts
    __shared__ unsigned short Cs[64 * 36];    // t2s staging
    int tid = threadIdx.x;
    int node0 = blockIdx.x * 64;
    if (tid < 65) lrp[tid] = rowptr[min(node0 + tid, N_NODES)];
    __syncthreads();
    int s0 = lrp[0];
    int cnt = lrp[64] - s0; if (cnt > AGG_CAP) cnt = AGG_CAP;
    for (int k = tid; k < cnt; k += 256) lcol[k] = col[s0 + k];
    if (tid < 64) {
        int n = node0 + tid;
        ldv[tid] = (n < N_NODES) ? dinv[n] : 0.f;
    }
    __syncthreads();
    int lane = tid & 63, w = tid >> 6;
    int grp = lane >> 3, fl = lane & 7;    // 8 groups/wave, 8 lanes/group (16B each)
    int gg = w * 8 + grp;                  // 0..31
    const uint4* t1q = (const uint4*)t1;   // row stride 8 uint4 (128B)
    float4 bb0 = ((const float4*)b1)[fl * 2];
    float4 bb1 = ((const float4*)b1)[fl * 2 + 1];
#pragma unroll
    for (int rep = 0; rep < 2; rep++) {
        int li = gg + rep * 32;
        int node = node0 + li;
        uint4 pk = make_uint4(0u, 0u, 0u, 0u);
        if (node < N_NODES) {
            int s = lrp[li] - s0;
            int e = lrp[li + 1] - s0; if (e > cnt) e = cnt;
            float a0 = 0.f, a1 = 0.f, a2 = 0.f, a3 = 0.f;
            float a4 = 0.f, a5 = 0.f, a6 = 0.f, a7 = 0.f;
            int p = s;
            for (; p + 3 < e; p += 4) {
                int c0 = lcol[p], c1 = lcol[p + 1], c2 = lcol[p + 2], c3 = lcol[p + 3];
                uint4 u0 = t1q[(size_t)c0 * 8 + fl];
                uint4 u1 = t1q[(size_t)c1 * 8 + fl];
                uint4 u2 = t1q[(size_t)c2 * 8 + fl];
                uint4 u3 = t1q[(size_t)c3 * 8 + fl];
                ACC8(u0); ACC8(u1); ACC8(u2); ACC8(u3);
            }
            for (; p < e; p++) {
                uint4 u = t1q[(size_t)lcol[p] * 8 + fl];
                ACC8(u);
            }
            uint4 us = t1q[(size_t)node * 8 + fl];   // self (already dinv-scaled)
            float di = ldv[li];
            float o0 = fmaxf(di * (a0 + bflo(us.x)) + bb0.x, 0.f);
            float o1 = fmaxf(di * (a1 + bfhi(us.x)) + bb0.y, 0.f);
            float o2 = fmaxf(di * (a2 + bflo(us.y)) + bb0.z, 0.f);
            float o3 = fmaxf(di * (a3 + bfhi(us.y)) + bb0.w, 0.f);
            float o4 = fmaxf(di * (a4 + bflo(us.z)) + bb1.x, 0.f);
            float o5 = fmaxf(di * (a5 + bfhi(us.z)) + bb1.y, 0.f);
            float o6 = fmaxf(di * (a6 + bflo(us.w)) + bb1.z, 0.f);
            float o7 = fmaxf(di * (a7 + bfhi(us.w)) + bb1.w, 0.f);
            pk.x = pack2bf(o0, o1);
            pk.y = pack2bf(o2, o3);
            pk.z = pack2bf(o4, o5);
            pk.w = pack2bf(o6, o7);
        }
        *(uint4*)&h1s[li * 72 + fl * 8] = pk;
    }
    __syncthreads();
    // ---- gemm2 MFMA: K=64 (2 steps), N=32 (2 tiles) ----
    int m = lane & 15, quad = lane >> 4;
    int row = w * 16 + m;
    f32x4 acc0 = {0.f, 0.f, 0.f, 0.f};
    f32x4 acc1 = acc0;
#pragma unroll
    for (int ks = 0; ks < 2; ks++) {
        int kb = ks * 32 + quad * 8;
        bf16x8 a  = *(const bf16x8*)&h1s[row * 72 + kb];
        bf16x8 b0 = *(const bf16x8*)&Wt2[(0 * 16 + m) * HID_F + kb];
        bf16x8 b1v = *(const bf16x8*)&Wt2[(1 * 16 + m) * HID_F + kb];
        acc0 = __builtin_amdgcn_mfma_f32_16x16x32_bf16(a, b0, acc0, 0, 0, 0);
        acc1 = __builtin_amdgcn_mfma_f32_16x16x32_bf16(a, b1v, acc1, 0, 0, 0);
    }
    int rbase = w * 16 + quad * 4;
#pragma unroll
    for (int reg = 0; reg < 4; reg++) {
        int r = rbase + reg;
        float d = ldv[r];
        Cs[r * 36 +  0 + m] = f2bf(acc0[reg] * d);
        Cs[r * 36 + 16 + m] = f2bf(acc1[reg] * d);
    }
    __syncthreads();
#pragma unroll
    for (int it = 0; it < 2; it++) {
        int idx = it * 256 + tid;
        int r = idx >> 3, c = idx & 7;
        int nd = node0 + r;
        if (nd < N_NODES) {
            uint2 vv = *(const uint2*)&Cs[r * 36 + c * 4];
            *(uint2*)&t2s[(size_t)nd * Z_F + c * 4] = vv;
        }
    }
}

// ---------------- FUSED agg2+heads: h2 lives in LDS only; emits out --------------
// Phase A (agg2): 4-lane group = node, lane fo holds feats 8fo..8fo+7 (uint4 gather).
// Phase B (heads): MFMA h2s @ Wth(+bias) -> out [mu|lv].
__global__ __launch_bounds__(256) void agg2heads_kernel(const unsigned short* __restrict__ t2s,
                                                        const int* __restrict__ rowptr,
                                                        const int* __restrict__ col,
                                                        const float* __restrict__ dinv,
                                                        const float* __restrict__ b2,
                                                        const unsigned short* __restrict__ Wth,
                                                        const float* __restrict__ bmu,
                                                        const float* __restrict__ blv,
                                                        float* __restrict__ out) {
    __shared__ int lcol[AGG_CAP];
    __shared__ int lrp[65];
    __shared__ float ldv[64];
    __shared__ unsigned short h2s[64 * 40];   // bf16 h2 tile, row stride 40 shorts
    __shared__ float Cf[64 * 68];             // out staging
    __shared__ float bias[64];
    int tid = threadIdx.x;
    int node0 = blockIdx.x * 64;
    if (tid < 65) lrp[tid] = rowptr[min(node0 + tid, N_NODES)];
    else if (tid >= 96 && tid < 128) bias[tid - 96] = bmu[tid - 96];
    else if (tid >= 128 && tid < 160) bias[tid - 96] = blv[tid - 128];
    __syncthreads();
    int s0 = lrp[0];
    int cnt = lrp[64] - s0; if (cnt > AGG_CAP) cnt = AGG_CAP;
    for (int k = tid; k < cnt; k += 256) lcol[k] = col[s0 + k];
    if (tid < 64) {
        int n = node0 + tid;
        ldv[tid] = (n < N_NODES) ? dinv[n] : 0.f;
    }
    __syncthreads();
    int lane = tid & 63, w = tid >> 6;
    int grp = lane >> 2, fo = lane & 3;    // 16 groups/wave, 4 lanes/group (16B each)
    int li = w * 16 + grp;                 // 0..63, single rep
    const uint4* t2q = (const uint4*)t2s;  // row stride 4 uint4 (64B)
    float4 bb0 = ((const float4*)b2)[fo * 2];
    float4 bb1 = ((const float4*)b2)[fo * 2 + 1];
    {
        int node = node0 + li;
        uint4 pk = make_uint4(0u, 0u, 0u, 0u);
        if (node < N_NODES) {
            int s = lrp[li] - s0;
            int e = lrp[li + 1] - s0; if (e > cnt) e = cnt;
            float a0 = 0.f, a1 = 0.f, a2 = 0.f, a3 = 0.f;
            float a4 = 0.f, a5 = 0.f, a6 = 0.f, a7 = 0.f;
            int p = s;
            for (; p + 3 < e; p += 4) {
                int c0 = lcol[p], c1 = lcol[p + 1], c2 = lcol[p + 2], c3 = lcol[p + 3];
                uint4 u0 = t2q[(size_t)c0 * 4 + fo];
                uint4 u1 = t2q[(size_t)c1 * 4 + fo];
                uint4 u2 = t2q[(size_t)c2 * 4 + fo];
                uint4 u3 = t2q[(size_t)c3 * 4 + fo];
                ACC8(u0); ACC8(u1); ACC8(u2); ACC8(u3);
            }
            for (; p < e; p++) {
                uint4 u = t2q[(size_t)lcol[p] * 4 + fo];
                ACC8(u);
            }
            uint4 us = t2q[(size_t)node * 4 + fo];
            float di = ldv[li];
            float o0 = di * (a0 + bflo(us.x)) + bb0.x;
            float o1 = di * (a1 + bfhi(us.x)) + bb0.y;
            float o2 = di * (a2 + bflo(us.y)) + bb0.z;
            float o3 = di * (a3 + bfhi(us.y)) + bb0.w;
            float o4 = di * (a4 + bflo(us.z)) + bb1.x;
            float o5 = di * (a5 + bfhi(us.z)) + bb1.y;
            float o6 = di * (a6 + bflo(us.w)) + bb1.z;
            float o7 = di * (a7 + bfhi(us.w)) + bb1.w;
            pk.x = pack2bf(o0, o1);
            pk.y = pack2bf(o2, o3);
            pk.z = pack2bf(o4, o5);
            pk.w = pack2bf(o6, o7);
        }
        *(uint4*)&h2s[li * 40 + fo * 8] = pk;
    }
    __syncthreads();
    // ---- heads MFMA: K=32 (1 step), N=64 (4 tiles: mu 0-31, lv 32-63) ----
    int m = lane & 15, quad = lane >> 4;
    int row = w * 16 + m;
    int kb = quad * 8;
    bf16x8 a  = *(const bf16x8*)&h2s[row * 40 + kb];
    bf16x8 b0 = *(const bf16x8*)&Wth[(0 * 16 + m) * Z_F + kb];
    bf16x8 b1 = *(const bf16x8*)&Wth[(1 * 16 + m) * Z_F + kb];
    bf16x8 b2v = *(const bf16x8*)&Wth[(2 * 16 + m) * Z_F + kb];
    bf16x8 b3 = *(const bf16x8*)&Wth[(3 * 16 + m) * Z_F + kb];
    f32x4 acc0 = {0.f, 0.f, 0.f, 0.f};
    f32x4 acc1 = acc0, acc2 = acc0, acc3 = acc0;
    acc0 = __builtin_amdgcn_mfma_f32_16x16x32_bf16(a, b0, acc0, 0, 0, 0);
    acc1 = __builtin_amdgcn_mfma_f32_16x16x32_bf16(a, b1, acc1, 0, 0, 0);
    acc2 = __builtin_amdgcn_mfma_f32_16x16x32_bf16(a, b2v, acc2, 0, 0, 0);
    acc3 = __builtin_amdgcn_mfma_f32_16x16x32_bf16(a, b3, acc3, 0, 0, 0);
    int rbase = w * 16 + quad * 4;
#pragma unroll
    for (int reg = 0; reg < 4; reg++) {
        int r = rbase + reg;
        Cf[r * 68 +  0 + m] = acc0[reg] + bias[ 0 + m];
        Cf[r * 68 + 16 + m] = acc1[reg] + bias[16 + m];
        Cf[r * 68 + 32 + m] = acc2[reg] + bias[32 + m];
        Cf[r * 68 + 48 + m] = acc3[reg] + bias[48 + m];
    }
    __syncthreads();
#pragma unroll
    for (int it = 0; it < 2; it++) {
        int idx = it * 256 + tid;
        int r = idx >> 3, c = idx & 7;
        int nd = node0 + r;
        if (nd < N_NODES) {
            float4 vmu = *(const float4*)&Cf[r * 68 + c * 4];
            float4 vlv = *(const float4*)&Cf[r * 68 + 32 + c * 4];
            *(float4*)&out[(size_t)nd * Z_F + c * 4] = vmu;
            *(float4*)&out[(size_t)N_NODES * Z_F + (size_t)nd * Z_F + c * 4] = vlv;
        }
    }
}

extern "C" void kernel_launch(void* const* d_in, const int* in_sizes, int n_in,
                              void* d_out, int out_size, void* d_ws, size_t ws_size,
                              hipStream_t stream) {
    const float* x   = (const float*)d_in[0];
    const int*   ei  = (const int*)d_in[1];
    const float* W1  = (const float*)d_in[2];
    const float* b1  = (const float*)d_in[3];
    const float* W2  = (const float*)d_in[4];
    const float* b2  = (const float*)d_in[5];
    const float* Wmu = (const float*)d_in[6];
    const float* bmu = (const float*)d_in[7];
    const float* Wlv = (const float*)d_in[8];
    const float* blv = (const float*)d_in[9];
    float* out = (float*)d_out;

    char* ws = (char*)d_ws;
    size_t off = 0;
    auto A = [&](size_t bytes) {
        size_t r = off;
        off += (bytes + 255) & ~(size_t)255;
        return r;
    };
    int*   gcur   = (int*)(ws + A((size_t)NBUK * 4));
    int*   rowptr = (int*)(ws + A((size_t)(N_NODES + 1) * 4));
    float* dinv   = (float*)(ws + A((size_t)N_NODES * 4));
    unsigned short* Wt1 = (unsigned short*)(ws + A((size_t)IN_F * HID_F * 2));
    unsigned short* Wt2 = (unsigned short*)(ws + A((size_t)HID_F * Z_F * 2));
    unsigned short* Wth = (unsigned short*)(ws + A((size_t)Z_F * 64 * 2));
    int*   col        = (int*)(ws + A((size_t)N_EDGES * 4));                    // 6.4 MB
    char*  reg1 = ws + A((size_t)NBUK * BCAP * 4);                              // 9.6 MB: pairs -> t2s
    uint32* pairs = (uint32*)reg1;                // dead after p2g1
    unsigned short* t2s = (unsigned short*)reg1;  // 6.4 MB, written by agg1gemm2
    unsigned short* t1 = (unsigned short*)(ws + A((size_t)N_NODES * HID_F * 2)); // 12.8 MB

    hipMemsetAsync(gcur, 0, (size_t)NBUK * 4, stream);

    phase1_kernel<<<P1_BLOCKS + 1, 512, 0, stream>>>(ei, gcur, pairs,
                                                     W1, W2, Wmu, Wlv, Wt1, Wt2, Wth);
    p2g1_kernel<<<NBUK + G1_BLOCKS, 256, 0, stream>>>(pairs, gcur, rowptr, dinv, col,
                                                      x, Wt1, t1);
    agg1gemm2_kernel<<<G1_BLOCKS, 256, 0, stream>>>(t1, rowptr, col, dinv, b1, Wt2, t2s);
    agg2heads_kernel<<<G1_BLOCKS, 256, 0, stream>>>(t2s, rowptr, col, dinv, b2, Wth, bmu, blv, out);
}